// Round 1
// baseline (355.974 us; speedup 1.0000x reference)
//
#include <hip/hip_runtime.h>

// DCNv1 on MI355X. fp32 throughout (no fp32 MFMA on CDNA4 -> VALU GEMM).
// Shapes fixed by the problem: B=4, C=64, H=W=128, Cout=64, K=3x3, stride=1, pad=1.

constexpr int B_  = 4;
constexpr int C_  = 64;
constexpr int H_  = 128;
constexpr int W_  = 128;
constexpr int CO_ = 64;
constexpr int K_  = 9;     // 3x3
constexpr int HW_ = H_ * W_;

// ---------------- workspace layout (floats) ----------------
// xt  : NHWC x                  [B][H][W][C]        4*128*128*64 = 4,194,304
// off : offsets, pixel-major    [B][H][W][18]       4*128*128*18 = 1,179,648
// wt  : w_d transposed          [k][c][oc]          9*64*64      = 36,864
// wpt : w_p transposed          [c][tap][j]         64*9*18      = 10,368
constexpr size_t XT_OFF  = 0;
constexpr size_t OFF_OFF = XT_OFF + (size_t)B_ * HW_ * C_;
constexpr size_t WT_OFF  = OFF_OFF + (size_t)B_ * HW_ * 18;
constexpr size_t WPT_OFF = WT_OFF + (size_t)K_ * C_ * CO_;

// ---------------- K0a: x NCHW -> NHWC ----------------
__global__ __launch_bounds__(256) void transpose_x_k(const float* __restrict__ x,
                                                     float* __restrict__ xt) {
    __shared__ float tile[64][65];  // +1 pad: conflict-free transposed read
    int bid = blockIdx.x;           // B*H*(W/64) = 1024
    int wt  = bid & 1;
    int h   = (bid >> 1) & 127;
    int b   = bid >> 8;
    int w0  = wt * 64;
    int tid = threadIdx.x;

    int lw = tid & 63;              // lane along w -> coalesced read
    int c0 = tid >> 6;              // 0..3
#pragma unroll
    for (int i = 0; i < 16; ++i) {
        int c = c0 * 16 + i;
        tile[c][lw] = x[((b * C_ + c) * H_ + h) * W_ + w0 + lw];
    }
    __syncthreads();
    int lc = tid & 63;              // lane along c -> coalesced write
    int wp = tid >> 6;
#pragma unroll
    for (int i = 0; i < 16; ++i) {
        int w = wp * 16 + i;
        xt[((size_t)(b * H_ + h) * W_ + w0 + w) * C_ + lc] = tile[lc][w];
    }
}

// ---------------- K0b: weight transposes (tiny) ----------------
__global__ void transpose_w_k(const float* __restrict__ wd, const float* __restrict__ wp,
                              float* __restrict__ wt, float* __restrict__ wpt) {
    int i = blockIdx.x * 256 + threadIdx.x;
    if (i < K_ * C_ * CO_) {                 // 36864: wt[k][c][oc] = wd[oc][c][k]
        int k  = i / (C_ * CO_);
        int r  = i % (C_ * CO_);
        int c  = r / CO_;
        int oc = r % CO_;
        wt[i] = wd[(oc * C_ + c) * K_ + k];
    }
    if (i < C_ * K_ * 18) {                  // 10368: wpt[c][t][j] = wp[j][c][ky][kx]
        int j = i % 18;
        int t = (i / 18) % K_;
        int c = i / (18 * K_);
        wpt[i] = wp[((j * C_ + c) * 3 + t / 3) * 3 + (t % 3)];
    }
}

// ---------------- K1: offset conv (18 channels per pixel-thread) ----------------
__global__ __launch_bounds__(256) void offset_conv_k(const float* __restrict__ x,
                                                     const float* __restrict__ wpt,
                                                     const float* __restrict__ bp,
                                                     float* __restrict__ off) {
    int tid = threadIdx.x;
    int wo  = tid & 127;            // lanes along W -> coalesced x reads
    int hh  = tid >> 7;
    int bid = blockIdx.x;           // 256 blocks = B * H/2
    int ho  = (bid & 63) * 2 + hh;
    int b   = bid >> 6;

    float acc[18];
#pragma unroll
    for (int j = 0; j < 18; ++j) acc[j] = bp[j];

    for (int c = 0; c < C_; ++c) {
        const float* xb = x + (size_t)(b * C_ + c) * HW_;
#pragma unroll
        for (int t = 0; t < 9; ++t) {
            int y  = ho + t / 3 - 1;
            int xw = wo + (t % 3) - 1;
            float xv = (y >= 0 && y < H_ && xw >= 0 && xw < W_) ? xb[y * W_ + xw] : 0.f;
            const float* wrow = wpt + (c * 9 + t) * 18;   // wave-uniform -> s_load
#pragma unroll
            for (int j = 0; j < 18; ++j) acc[j] = fmaf(xv, wrow[j], acc[j]);
        }
    }
    size_t p = (size_t)(b * H_ + ho) * W_ + wo;
#pragma unroll
    for (int j = 0; j < 18; ++j) off[p * 18 + j] = acc[j];
}

// ---------------- K2: deformable sampling + GEMM ----------------
// Block: 64 consecutive pixels (one half-row) x all 64 oc. 256 threads.
// Per k-tap: stage samp[c][pix] (bilinear from NHWC x) + w[c][oc] in LDS,
// then 64x64x64 outer-product GEMM, 4x4 register tile per thread.
__global__ __launch_bounds__(256) void deform_gemm_k(const float* __restrict__ xt,
                                                     const float* __restrict__ off,
                                                     const float* __restrict__ wt,
                                                     float* __restrict__ out) {
    __shared__ float s_samp[64][64];  // [c][pix]
    __shared__ float s_w[64][64];     // [c][oc]

    int tid = threadIdx.x;
    int p0  = blockIdx.x * 64;       // 1024 blocks
    int wo0 = p0 & 127;              // 0 or 64
    int ho  = (p0 >> 7) & 127;
    int b   = p0 >> 14;

    // staging roles
    int pix = tid & 63;
    int cg  = tid >> 6;              // c-chunk of 16
    // GEMM roles
    int gp = (tid & 15) * 4;         // pixel quad
    int go = (tid >> 4) * 4;         // oc quad

    float4 acc[4];                   // acc[oi] = {pix0..pix3}
#pragma unroll
    for (int i = 0; i < 4; ++i) acc[i] = make_float4(0.f, 0.f, 0.f, 0.f);

    for (int k = 0; k < 9; ++k) {
        // ---- stage w tile: 4096 floats coalesced ----
        const float4* wsrc = (const float4*)(wt + k * 4096);
        float4* wdst = (float4*)&s_w[0][0];
#pragma unroll
        for (int i = 0; i < 4; ++i) wdst[i * 256 + tid] = wsrc[i * 256 + tid];

        // ---- stage samp tile: bilinear sample 16 channels per thread ----
        {
            int p = p0 + pix;
            float oy = off[(size_t)p * 18 + 2 * k];
            float ox = off[(size_t)p * 18 + 2 * k + 1];
            float py = oy + (float)(ho - 1 + k / 3);
            float px = ox + (float)(wo0 + pix - 1 + (k % 3));
            float fy = floorf(py), fx = floorf(px);
            float wy = py - fy, wx = px - fx;
            int y0 = (int)fy, x0 = (int)fx;
            int y1 = y0 + 1,  x1 = x0 + 1;
            float w00 = (1.f - wy) * (1.f - wx);
            float w01 = (1.f - wy) * wx;
            float w10 = wy * (1.f - wx);
            float w11 = wy * wx;
            bool vy0 = (y0 >= 0) & (y0 < H_), vy1 = (y1 >= 0) & (y1 < H_);
            bool vx0 = (x0 >= 0) & (x0 < W_), vx1 = (x1 >= 0) & (x1 < W_);
            w00 *= (float)(vy0 & vx0);
            w01 *= (float)(vy0 & vx1);
            w10 *= (float)(vy1 & vx0);
            w11 *= (float)(vy1 & vx1);
            int cy0 = min(max(y0, 0), H_ - 1), cy1 = min(max(y1, 0), H_ - 1);
            int cx0 = min(max(x0, 0), W_ - 1), cx1 = min(max(x1, 0), W_ - 1);
            size_t base = (size_t)(b * H_) * W_ * C_;
            const float4* p00 = (const float4*)(xt + base + ((size_t)cy0 * W_ + cx0) * C_ + cg * 16);
            const float4* p01 = (const float4*)(xt + base + ((size_t)cy0 * W_ + cx1) * C_ + cg * 16);
            const float4* p10 = (const float4*)(xt + base + ((size_t)cy1 * W_ + cx0) * C_ + cg * 16);
            const float4* p11 = (const float4*)(xt + base + ((size_t)cy1 * W_ + cx1) * C_ + cg * 16);
#pragma unroll
            for (int i = 0; i < 4; ++i) {
                float4 a = p00[i], bq = p01[i], cq = p10[i], dq = p11[i];
                int c = cg * 16 + i * 4;
                s_samp[c + 0][pix] = w00 * a.x + w01 * bq.x + w10 * cq.x + w11 * dq.x;
                s_samp[c + 1][pix] = w00 * a.y + w01 * bq.y + w10 * cq.y + w11 * dq.y;
                s_samp[c + 2][pix] = w00 * a.z + w01 * bq.z + w10 * cq.z + w11 * dq.z;
                s_samp[c + 3][pix] = w00 * a.w + w01 * bq.w + w10 * cq.w + w11 * dq.w;
            }
        }
        __syncthreads();

        // ---- GEMM: acc[oi][pi] += w[c][go+oi] * samp[c][gp+pi] ----
#pragma unroll 8
        for (int c = 0; c < 64; ++c) {
            float4 s  = *(const float4*)&s_samp[c][gp];
            float4 wv = *(const float4*)&s_w[c][go];
            acc[0].x = fmaf(wv.x, s.x, acc[0].x);
            acc[0].y = fmaf(wv.x, s.y, acc[0].y);
            acc[0].z = fmaf(wv.x, s.z, acc[0].z);
            acc[0].w = fmaf(wv.x, s.w, acc[0].w);
            acc[1].x = fmaf(wv.y, s.x, acc[1].x);
            acc[1].y = fmaf(wv.y, s.y, acc[1].y);
            acc[1].z = fmaf(wv.y, s.z, acc[1].z);
            acc[1].w = fmaf(wv.y, s.w, acc[1].w);
            acc[2].x = fmaf(wv.z, s.x, acc[2].x);
            acc[2].y = fmaf(wv.z, s.y, acc[2].y);
            acc[2].z = fmaf(wv.z, s.z, acc[2].z);
            acc[2].w = fmaf(wv.z, s.w, acc[2].w);
            acc[3].x = fmaf(wv.w, s.x, acc[3].x);
            acc[3].y = fmaf(wv.w, s.y, acc[3].y);
            acc[3].z = fmaf(wv.w, s.z, acc[3].z);
            acc[3].w = fmaf(wv.w, s.w, acc[3].w);
        }
        __syncthreads();
    }

    // ---- epilogue: NCHW output, float4 stores, coalesced per 16-lane group ----
#pragma unroll
    for (int oi = 0; oi < 4; ++oi) {
        *(float4*)&out[((size_t)(b * CO_ + go + oi) * H_ + ho) * W_ + wo0 + gp] = acc[oi];
    }
}

extern "C" void kernel_launch(void* const* d_in, const int* in_sizes, int n_in,
                              void* d_out, int out_size, void* d_ws, size_t ws_size,
                              hipStream_t stream) {
    const float* x  = (const float*)d_in[0];
    const float* wp = (const float*)d_in[1];
    const float* bp = (const float*)d_in[2];
    const float* wd = (const float*)d_in[3];
    float* out = (float*)d_out;
    float* ws  = (float*)d_ws;

    float* xt  = ws + XT_OFF;
    float* off = ws + OFF_OFF;
    float* wt  = ws + WT_OFF;
    float* wpt = ws + WPT_OFF;

    transpose_x_k<<<B_ * H_ * (W_ / 64), 256, 0, stream>>>(x, xt);
    transpose_w_k<<<(K_ * C_ * CO_ + 255) / 256, 256, 0, stream>>>(wd, wp, wt, wpt);
    offset_conv_k<<<B_ * H_ / 2, 256, 0, stream>>>(x, wpt, bp, off);
    deform_gemm_k<<<B_ * HW_ / 64, 256, 0, stream>>>(xt, off, wt, out);
}

// Round 2
// 264.712 us; speedup vs baseline: 1.3448x; 1.3448x over previous
//
#include <hip/hip_runtime.h>

// DCNv1 on MI355X. fp32 throughout (no fp32 MFMA on CDNA4 -> VALU GEMM).
// Shapes fixed: B=4, C=64, H=W=128, Cout=64, K=3x3, stride=1, pad=1.

constexpr int B_  = 4;
constexpr int C_  = 64;
constexpr int H_  = 128;
constexpr int W_  = 128;
constexpr int CO_ = 64;
constexpr int K_  = 9;     // 3x3
constexpr int HW_ = H_ * W_;

// ---------------- workspace layout (floats) ----------------
constexpr size_t XT_OFF  = 0;                                   // NHWC x [B][H][W][C]
constexpr size_t OFF_OFF = XT_OFF + (size_t)B_ * HW_ * C_;      // offsets [B][H][W][18]
constexpr size_t WT_OFF  = OFF_OFF + (size_t)B_ * HW_ * 18;     // w_d^T [k][c][oc]
constexpr size_t WPT_OFF = WT_OFF + (size_t)K_ * C_ * CO_;      // w_p^T [c][t][j]

// ---------------- K0a: x NCHW -> NHWC ----------------
__global__ __launch_bounds__(256) void transpose_x_k(const float* __restrict__ x,
                                                     float* __restrict__ xt) {
    __shared__ float tile[64][65];
    int bid = blockIdx.x;           // B*H*(W/64) = 1024
    int wt  = bid & 1;
    int h   = (bid >> 1) & 127;
    int b   = bid >> 8;
    int w0  = wt * 64;
    int tid = threadIdx.x;

    int lw = tid & 63;
    int c0 = tid >> 6;
#pragma unroll
    for (int i = 0; i < 16; ++i) {
        int c = c0 * 16 + i;
        tile[c][lw] = x[((b * C_ + c) * H_ + h) * W_ + w0 + lw];
    }
    __syncthreads();
    int lc = tid & 63;
    int wp = tid >> 6;
#pragma unroll
    for (int i = 0; i < 16; ++i) {
        int w = wp * 16 + i;
        xt[((size_t)(b * H_ + h) * W_ + w0 + w) * C_ + lc] = tile[lc][w];
    }
}

// ---------------- K0b: weight transposes (tiny) ----------------
__global__ void transpose_w_k(const float* __restrict__ wd, const float* __restrict__ wp,
                              float* __restrict__ wt, float* __restrict__ wpt) {
    int i = blockIdx.x * 256 + threadIdx.x;
    if (i < K_ * C_ * CO_) {                 // wt[k][c][oc] = wd[oc][c][k]
        int k  = i / (C_ * CO_);
        int r  = i % (C_ * CO_);
        int c  = r / CO_;
        int oc = r % CO_;
        wt[i] = wd[(oc * C_ + c) * K_ + k];
    }
    if (i < C_ * K_ * 18) {                  // wpt[c][t][j] = wp[j][c][ky][kx]
        int j = i % 18;
        int t = (i / 18) % K_;
        int c = i / (18 * K_);
        wpt[i] = wp[((j * C_ + c) * 3 + t / 3) * 3 + (t % 3)];
    }
}

// ---------------- K1: offset conv v2 ----------------
// Block: 64 pixels (half row) x 4 c-quarters = 256 threads. Grid = B*H*2 = 1024.
// Each thread: 16 channels x 9 taps x 18 outputs, then LDS reduce over quarters.
__global__ __launch_bounds__(256) void offset_conv_k(const float* __restrict__ x,
                                                     const float* __restrict__ wpt,
                                                     const float* __restrict__ bp,
                                                     float* __restrict__ off) {
    __shared__ float red[4][64][19];   // [cq][pix][j], stride 19 -> conflict-free
    int tid = threadIdx.x;
    int pix = tid & 63;
    int cq  = tid >> 6;                // wave-uniform (wave = 64 lanes)
    int bid = blockIdx.x;
    int w0  = (bid & 1) * 64;
    int h   = (bid >> 1) & 127;
    int b   = bid >> 8;
    int wo  = w0 + pix;

    float acc[18];
#pragma unroll
    for (int j = 0; j < 18; ++j) acc[j] = 0.f;

    int c0 = cq * 16;
    for (int ci = 0; ci < 16; ++ci) {
        int c = c0 + ci;
        const float* xb = x + (size_t)(b * C_ + c) * HW_;
        const float* wr = wpt + (c * 9) * 18;   // wave-uniform base -> s_load path
#pragma unroll
        for (int t = 0; t < 9; ++t) {
            int y  = h + t / 3 - 1;
            int xw = wo + (t % 3) - 1;
            float xv = (y >= 0 && y < H_ && xw >= 0 && xw < W_) ? xb[y * W_ + xw] : 0.f;
            const float* wrow = wr + t * 18;
#pragma unroll
            for (int j = 0; j < 18; ++j) acc[j] = fmaf(xv, wrow[j], acc[j]);
        }
    }
#pragma unroll
    for (int j = 0; j < 18; ++j) red[cq][pix][j] = acc[j];
    __syncthreads();

    size_t base = ((size_t)(b * H_ + h) * W_ + w0) * 18;
#pragma unroll
    for (int it = 0; it < 5; ++it) {
        int idx = it * 256 + tid;             // p*18 + j, 0..1151
        if (idx < 64 * 18) {
            int p = idx / 18, j = idx % 18;
            float s = red[0][p][j] + red[1][p][j] + red[2][p][j] + red[3][p][j] + bp[j];
            off[base + idx] = s;
        }
    }
}

// ---------------- K2: deformable sampling + GEMM v2 ----------------
// Block: 128 pixels (one full row) x 64 oc. 256 threads, 8pix x 4oc per thread.
// Grid = B*H = 512.
__global__ __launch_bounds__(256) void deform_gemm_k(const float* __restrict__ xt,
                                                     const float* __restrict__ off,
                                                     const float* __restrict__ wt,
                                                     float* __restrict__ out) {
    __shared__ float s_samp[64][128];  // [c][pix] 32KB
    __shared__ float s_w[64][64];      // [c][oc]  16KB

    int tid = threadIdx.x;
    int h   = blockIdx.x & 127;
    int b   = blockIdx.x >> 7;

    // staging roles: 2 threads per pixel, 32 channels each
    int spix = tid & 127;
    int sc   = tid >> 7;               // 0/1 -> channel half
    // GEMM roles: 8 pixels x 4 oc per thread
    int tp  = tid & 15;
    int to  = tid >> 4;
    int gp0 = tp * 8;
    int oc0 = to * 4;

    float4 acc[8];                     // acc[pi] = 4 oc values
#pragma unroll
    for (int i = 0; i < 8; ++i) acc[i] = make_float4(0.f, 0.f, 0.f, 0.f);

    size_t obase = ((size_t)(b * H_ + h) * W_ + spix) * 18;
    const float* xb = xt + (size_t)b * HW_ * C_;

    for (int k = 0; k < 9; ++k) {
        // ---- stage w tile ----
        const float4* wsrc = (const float4*)(wt + k * 4096);
        float4* wdst = (float4*)&s_w[0][0];
#pragma unroll
        for (int i = 0; i < 4; ++i) wdst[i * 256 + tid] = wsrc[i * 256 + tid];

        // ---- stage samp tile (bilinear, 32 channels per thread) ----
        {
            float2 o2 = *(const float2*)(off + obase + 2 * k);
            float py = o2.x + (float)(h - 1 + k / 3);
            float px = o2.y + (float)(spix - 1 + (k % 3));
            float fy = floorf(py), fx = floorf(px);
            float wy = py - fy, wx = px - fx;
            int y0 = (int)fy, x0 = (int)fx;
            int y1 = y0 + 1,  x1 = x0 + 1;
            float w00 = (1.f - wy) * (1.f - wx);
            float w01 = (1.f - wy) * wx;
            float w10 = wy * (1.f - wx);
            float w11 = wy * wx;
            bool vy0 = (y0 >= 0) & (y0 < H_), vy1 = (y1 >= 0) & (y1 < H_);
            bool vx0 = (x0 >= 0) & (x0 < W_), vx1 = (x1 >= 0) & (x1 < W_);
            w00 *= (float)(vy0 & vx0);
            w01 *= (float)(vy0 & vx1);
            w10 *= (float)(vy1 & vx0);
            w11 *= (float)(vy1 & vx1);
            int cy0 = min(max(y0, 0), H_ - 1), cy1 = min(max(y1, 0), H_ - 1);
            int cx0 = min(max(x0, 0), W_ - 1), cx1 = min(max(x1, 0), W_ - 1);
            int c0 = sc * 32;
            const float4* p00 = (const float4*)(xb + ((size_t)cy0 * W_ + cx0) * C_ + c0);
            const float4* p01 = (const float4*)(xb + ((size_t)cy0 * W_ + cx1) * C_ + c0);
            const float4* p10 = (const float4*)(xb + ((size_t)cy1 * W_ + cx0) * C_ + c0);
            const float4* p11 = (const float4*)(xb + ((size_t)cy1 * W_ + cx1) * C_ + c0);
#pragma unroll
            for (int i = 0; i < 8; ++i) {
                float4 a = p00[i], bq = p01[i], cq = p10[i], dq = p11[i];
                int c = c0 + i * 4;
                s_samp[c + 0][spix] = w00 * a.x + w01 * bq.x + w10 * cq.x + w11 * dq.x;
                s_samp[c + 1][spix] = w00 * a.y + w01 * bq.y + w10 * cq.y + w11 * dq.y;
                s_samp[c + 2][spix] = w00 * a.z + w01 * bq.z + w10 * cq.z + w11 * dq.z;
                s_samp[c + 3][spix] = w00 * a.w + w01 * bq.w + w10 * cq.w + w11 * dq.w;
            }
        }
        __syncthreads();

        // ---- GEMM: acc[pi] += s_w[c][oc0..3] * s_samp[c][gp0+pi] ----
#pragma unroll 4
        for (int c = 0; c < 64; ++c) {
            float4 wv = *(const float4*)&s_w[c][oc0];
            float4 sa = *(const float4*)&s_samp[c][gp0];
            float4 sb = *(const float4*)&s_samp[c][gp0 + 4];
            acc[0].x = fmaf(wv.x, sa.x, acc[0].x);
            acc[0].y = fmaf(wv.y, sa.x, acc[0].y);
            acc[0].z = fmaf(wv.z, sa.x, acc[0].z);
            acc[0].w = fmaf(wv.w, sa.x, acc[0].w);
            acc[1].x = fmaf(wv.x, sa.y, acc[1].x);
            acc[1].y = fmaf(wv.y, sa.y, acc[1].y);
            acc[1].z = fmaf(wv.z, sa.y, acc[1].z);
            acc[1].w = fmaf(wv.w, sa.y, acc[1].w);
            acc[2].x = fmaf(wv.x, sa.z, acc[2].x);
            acc[2].y = fmaf(wv.y, sa.z, acc[2].y);
            acc[2].z = fmaf(wv.z, sa.z, acc[2].z);
            acc[2].w = fmaf(wv.w, sa.z, acc[2].w);
            acc[3].x = fmaf(wv.x, sa.w, acc[3].x);
            acc[3].y = fmaf(wv.y, sa.w, acc[3].y);
            acc[3].z = fmaf(wv.z, sa.w, acc[3].z);
            acc[3].w = fmaf(wv.w, sa.w, acc[3].w);
            acc[4].x = fmaf(wv.x, sb.x, acc[4].x);
            acc[4].y = fmaf(wv.y, sb.x, acc[4].y);
            acc[4].z = fmaf(wv.z, sb.x, acc[4].z);
            acc[4].w = fmaf(wv.w, sb.x, acc[4].w);
            acc[5].x = fmaf(wv.x, sb.y, acc[5].x);
            acc[5].y = fmaf(wv.y, sb.y, acc[5].y);
            acc[5].z = fmaf(wv.z, sb.y, acc[5].z);
            acc[5].w = fmaf(wv.w, sb.y, acc[5].w);
            acc[6].x = fmaf(wv.x, sb.z, acc[6].x);
            acc[6].y = fmaf(wv.y, sb.z, acc[6].y);
            acc[6].z = fmaf(wv.z, sb.z, acc[6].z);
            acc[6].w = fmaf(wv.w, sb.z, acc[6].w);
            acc[7].x = fmaf(wv.x, sb.w, acc[7].x);
            acc[7].y = fmaf(wv.y, sb.w, acc[7].y);
            acc[7].z = fmaf(wv.z, sb.w, acc[7].z);
            acc[7].w = fmaf(wv.w, sb.w, acc[7].w);
        }
        __syncthreads();
    }

    // ---- epilogue: NCHW output, two float4 stores per oc ----
#pragma unroll
    for (int oi = 0; oi < 4; ++oi) {
        float* op = out + ((size_t)(b * CO_ + oc0 + oi) * H_ + h) * W_ + gp0;
        float4 v0, v1;
        v0.x = (&acc[0].x)[oi]; v0.y = (&acc[1].x)[oi];
        v0.z = (&acc[2].x)[oi]; v0.w = (&acc[3].x)[oi];
        v1.x = (&acc[4].x)[oi]; v1.y = (&acc[5].x)[oi];
        v1.z = (&acc[6].x)[oi]; v1.w = (&acc[7].x)[oi];
        *(float4*)op = v0;
        *(float4*)(op + 4) = v1;
    }
}

extern "C" void kernel_launch(void* const* d_in, const int* in_sizes, int n_in,
                              void* d_out, int out_size, void* d_ws, size_t ws_size,
                              hipStream_t stream) {
    const float* x  = (const float*)d_in[0];
    const float* wp = (const float*)d_in[1];
    const float* bp = (const float*)d_in[2];
    const float* wd = (const float*)d_in[3];
    float* out = (float*)d_out;
    float* ws  = (float*)d_ws;

    float* xt  = ws + XT_OFF;
    float* off = ws + OFF_OFF;
    float* wt  = ws + WT_OFF;
    float* wpt = ws + WPT_OFF;

    transpose_x_k<<<B_ * H_ * (W_ / 64), 256, 0, stream>>>(x, xt);
    transpose_w_k<<<(K_ * C_ * CO_ + 255) / 256, 256, 0, stream>>>(wd, wp, wt, wpt);
    offset_conv_k<<<B_ * H_ * 2, 256, 0, stream>>>(x, wpt, bp, off);
    deform_gemm_k<<<B_ * H_, 256, 0, stream>>>(xt, off, wt, out);
}

// Round 3
// 253.758 us; speedup vs baseline: 1.4028x; 1.0432x over previous
//
#include <hip/hip_runtime.h>

// DCNv1 on MI355X. fp32 throughout (no fp32 MFMA on CDNA4 -> VALU GEMM).
// Shapes fixed: B=4, C=64, H=W=128, Cout=64, K=3x3, stride=1, pad=1.

constexpr int B_  = 4;
constexpr int C_  = 64;
constexpr int H_  = 128;
constexpr int W_  = 128;
constexpr int CO_ = 64;
constexpr int K_  = 9;     // 3x3
constexpr int HW_ = H_ * W_;

// ---------------- workspace layout (floats) ----------------
constexpr size_t XT_OFF  = 0;                                   // NHWC x [B][H][W][C]
constexpr size_t OFF_OFF = XT_OFF + (size_t)B_ * HW_ * C_;      // offsets [B][H][W][18]
constexpr size_t WT_OFF  = OFF_OFF + (size_t)B_ * HW_ * 18;     // w_d^T [k][c][oc]
constexpr size_t WPT_OFF = WT_OFF + (size_t)K_ * C_ * CO_;      // w_p^T [c][t][j]

// ---------------- K0a: x NCHW -> NHWC ----------------
__global__ __launch_bounds__(256) void transpose_x_k(const float* __restrict__ x,
                                                     float* __restrict__ xt) {
    __shared__ float tile[64][65];
    int bid = blockIdx.x;           // B*H*(W/64) = 1024
    int wt  = bid & 1;
    int h   = (bid >> 1) & 127;
    int b   = bid >> 8;
    int w0  = wt * 64;
    int tid = threadIdx.x;

    int lw = tid & 63;
    int c0 = tid >> 6;
#pragma unroll
    for (int i = 0; i < 16; ++i) {
        int c = c0 * 16 + i;
        tile[c][lw] = x[((b * C_ + c) * H_ + h) * W_ + w0 + lw];
    }
    __syncthreads();
    int lc = tid & 63;
    int wp = tid >> 6;
#pragma unroll
    for (int i = 0; i < 16; ++i) {
        int w = wp * 16 + i;
        xt[((size_t)(b * H_ + h) * W_ + w0 + w) * C_ + lc] = tile[lc][w];
    }
}

// ---------------- K0b: weight transposes (tiny) ----------------
__global__ void transpose_w_k(const float* __restrict__ wd, const float* __restrict__ wp,
                              float* __restrict__ wt, float* __restrict__ wpt) {
    int i = blockIdx.x * 256 + threadIdx.x;
    if (i < K_ * C_ * CO_) {                 // wt[k][c][oc] = wd[oc][c][k]
        int k  = i / (C_ * CO_);
        int r  = i % (C_ * CO_);
        int c  = r / CO_;
        int oc = r % CO_;
        wt[i] = wd[(oc * C_ + c) * K_ + k];
    }
    if (i < C_ * K_ * 18) {                  // wpt[c][t][j] = wp[j][c][ky][kx]
        int j = i % 18;
        int t = (i / 18) % K_;
        int c = i / (18 * K_);
        wpt[i] = wp[((j * C_ + c) * 3 + t / 3) * 3 + (t % 3)];
    }
}

// ---------------- K1: offset conv (unchanged this round) ----------------
__global__ __launch_bounds__(256) void offset_conv_k(const float* __restrict__ x,
                                                     const float* __restrict__ wpt,
                                                     const float* __restrict__ bp,
                                                     float* __restrict__ off) {
    __shared__ float red[4][64][19];
    int tid = threadIdx.x;
    int pix = tid & 63;
    int cq  = tid >> 6;
    int bid = blockIdx.x;
    int w0  = (bid & 1) * 64;
    int h   = (bid >> 1) & 127;
    int b   = bid >> 8;
    int wo  = w0 + pix;

    float acc[18];
#pragma unroll
    for (int j = 0; j < 18; ++j) acc[j] = 0.f;

    int c0 = cq * 16;
    for (int ci = 0; ci < 16; ++ci) {
        int c = c0 + ci;
        const float* xb = x + (size_t)(b * C_ + c) * HW_;
        const float* wr = wpt + (c * 9) * 18;
#pragma unroll
        for (int t = 0; t < 9; ++t) {
            int y  = h + t / 3 - 1;
            int xw = wo + (t % 3) - 1;
            float xv = (y >= 0 && y < H_ && xw >= 0 && xw < W_) ? xb[y * W_ + xw] : 0.f;
            const float* wrow = wr + t * 18;
#pragma unroll
            for (int j = 0; j < 18; ++j) acc[j] = fmaf(xv, wrow[j], acc[j]);
        }
    }
#pragma unroll
    for (int j = 0; j < 18; ++j) red[cq][pix][j] = acc[j];
    __syncthreads();

    size_t base = ((size_t)(b * H_ + h) * W_ + w0) * 18;
#pragma unroll
    for (int it = 0; it < 5; ++it) {
        int idx = it * 256 + tid;
        if (idx < 64 * 18) {
            int p = idx / 18, j = idx % 18;
            float s = red[0][p][j] + red[1][p][j] + red[2][p][j] + red[3][p][j] + bp[j];
            off[base + idx] = s;
        }
    }
}

// ---------------- K2: deformable sampling + GEMM v3 ----------------
// Block: 128 pixels (one full row) x 64 oc. 256 threads, 8pix x 4oc per thread.
// Pixel split {tp*4, 64+tp*4} -> conflict-free ds_read_b128.
// XCD swizzle: each XCD owns a 64-row slab of one image (2.1MB, L2-resident).
__global__ __launch_bounds__(256) void deform_gemm_k(const float* __restrict__ xt,
                                                     const float* __restrict__ off,
                                                     const float* __restrict__ wt,
                                                     float* __restrict__ out) {
    __shared__ float s_samp[64][128];  // [c][pix] 32KB
    __shared__ float s_w[64][64];      // [c][oc]  16KB

    int tid = threadIdx.x;
    // XCD-aware mapping: bid&7 = XCD (dispatch round-robin); each XCD gets
    // one 64-row slab of one image. bijective over (b,h).
    int bid = blockIdx.x;              // 0..511
    int xcd = bid & 7;
    int b   = xcd >> 1;
    int h   = (bid >> 3) | ((xcd & 1) << 6);

    // staging roles: 2 threads per pixel, 32 channels each
    int spix = tid & 127;
    int sc   = tid >> 7;
    // GEMM roles: 8 pixels (split 4+4) x 4 oc per thread
    int tp  = tid & 15;
    int to  = tid >> 4;                // 0..15
    int gpa = tp * 4;                  // pixels gpa..gpa+3
    int gpb = 64 + tp * 4;             // pixels gpb..gpb+3
    int oc0 = to * 4;

    float4 acc[8];                     // [0..3]=gpa pix, [4..7]=gpb pix; each = 4 oc
#pragma unroll
    for (int i = 0; i < 8; ++i) acc[i] = make_float4(0.f, 0.f, 0.f, 0.f);

    size_t obase = ((size_t)(b * H_ + h) * W_ + spix) * 18;
    const float* xb = xt + (size_t)b * HW_ * C_;

    for (int k = 0; k < 9; ++k) {
        // ---- stage w tile ----
        const float4* wsrc = (const float4*)(wt + k * 4096);
        float4* wdst = (float4*)&s_w[0][0];
#pragma unroll
        for (int i = 0; i < 4; ++i) wdst[i * 256 + tid] = wsrc[i * 256 + tid];

        // ---- stage samp tile (bilinear, 32 channels per thread) ----
        {
            float2 o2 = *(const float2*)(off + obase + 2 * k);
            float py = o2.x + (float)(h - 1 + k / 3);
            float px = o2.y + (float)(spix - 1 + (k % 3));
            float fy = floorf(py), fx = floorf(px);
            float wy = py - fy, wx = px - fx;
            int y0 = (int)fy, x0 = (int)fx;
            int y1 = y0 + 1,  x1 = x0 + 1;
            float w00 = (1.f - wy) * (1.f - wx);
            float w01 = (1.f - wy) * wx;
            float w10 = wy * (1.f - wx);
            float w11 = wy * wx;
            bool vy0 = (y0 >= 0) & (y0 < H_), vy1 = (y1 >= 0) & (y1 < H_);
            bool vx0 = (x0 >= 0) & (x0 < W_), vx1 = (x1 >= 0) & (x1 < W_);
            w00 *= (float)(vy0 & vx0);
            w01 *= (float)(vy0 & vx1);
            w10 *= (float)(vy1 & vx0);
            w11 *= (float)(vy1 & vx1);
            int cy0 = min(max(y0, 0), H_ - 1), cy1 = min(max(y1, 0), H_ - 1);
            int cx0 = min(max(x0, 0), W_ - 1), cx1 = min(max(x1, 0), W_ - 1);
            int c0 = sc * 32;
            const float4* p00 = (const float4*)(xb + ((size_t)cy0 * W_ + cx0) * C_ + c0);
            const float4* p01 = (const float4*)(xb + ((size_t)cy0 * W_ + cx1) * C_ + c0);
            const float4* p10 = (const float4*)(xb + ((size_t)cy1 * W_ + cx0) * C_ + c0);
            const float4* p11 = (const float4*)(xb + ((size_t)cy1 * W_ + cx1) * C_ + c0);
#pragma unroll
            for (int i = 0; i < 8; ++i) {
                float4 a = p00[i], bq = p01[i], cq = p10[i], dq = p11[i];
                int c = c0 + i * 4;
                s_samp[c + 0][spix] = w00 * a.x + w01 * bq.x + w10 * cq.x + w11 * dq.x;
                s_samp[c + 1][spix] = w00 * a.y + w01 * bq.y + w10 * cq.y + w11 * dq.y;
                s_samp[c + 2][spix] = w00 * a.z + w01 * bq.z + w10 * cq.z + w11 * dq.z;
                s_samp[c + 3][spix] = w00 * a.w + w01 * bq.w + w10 * cq.w + w11 * dq.w;
            }
        }
        __syncthreads();

        // ---- GEMM: conflict-free b128 reads (16 addr x 16B stride) ----
#pragma unroll 4
        for (int c = 0; c < 64; ++c) {
            float4 wv = *(const float4*)&s_w[c][oc0];
            float4 sa = *(const float4*)&s_samp[c][gpa];
            float4 sb = *(const float4*)&s_samp[c][gpb];
            acc[0].x = fmaf(wv.x, sa.x, acc[0].x);
            acc[0].y = fmaf(wv.y, sa.x, acc[0].y);
            acc[0].z = fmaf(wv.z, sa.x, acc[0].z);
            acc[0].w = fmaf(wv.w, sa.x, acc[0].w);
            acc[1].x = fmaf(wv.x, sa.y, acc[1].x);
            acc[1].y = fmaf(wv.y, sa.y, acc[1].y);
            acc[1].z = fmaf(wv.z, sa.y, acc[1].z);
            acc[1].w = fmaf(wv.w, sa.y, acc[1].w);
            acc[2].x = fmaf(wv.x, sa.z, acc[2].x);
            acc[2].y = fmaf(wv.y, sa.z, acc[2].y);
            acc[2].z = fmaf(wv.z, sa.z, acc[2].z);
            acc[2].w = fmaf(wv.w, sa.z, acc[2].w);
            acc[3].x = fmaf(wv.x, sa.w, acc[3].x);
            acc[3].y = fmaf(wv.y, sa.w, acc[3].y);
            acc[3].z = fmaf(wv.z, sa.w, acc[3].z);
            acc[3].w = fmaf(wv.w, sa.w, acc[3].w);
            acc[4].x = fmaf(wv.x, sb.x, acc[4].x);
            acc[4].y = fmaf(wv.y, sb.x, acc[4].y);
            acc[4].z = fmaf(wv.z, sb.x, acc[4].z);
            acc[4].w = fmaf(wv.w, sb.x, acc[4].w);
            acc[5].x = fmaf(wv.x, sb.y, acc[5].x);
            acc[5].y = fmaf(wv.y, sb.y, acc[5].y);
            acc[5].z = fmaf(wv.z, sb.y, acc[5].z);
            acc[5].w = fmaf(wv.w, sb.y, acc[5].w);
            acc[6].x = fmaf(wv.x, sb.z, acc[6].x);
            acc[6].y = fmaf(wv.y, sb.z, acc[6].y);
            acc[6].z = fmaf(wv.z, sb.z, acc[6].z);
            acc[6].w = fmaf(wv.w, sb.z, acc[6].w);
            acc[7].x = fmaf(wv.x, sb.w, acc[7].x);
            acc[7].y = fmaf(wv.y, sb.w, acc[7].y);
            acc[7].z = fmaf(wv.z, sb.w, acc[7].z);
            acc[7].w = fmaf(wv.w, sb.w, acc[7].w);
        }
        __syncthreads();
    }

    // ---- epilogue: NCHW output, two float4 stores per oc ----
#pragma unroll
    for (int oi = 0; oi < 4; ++oi) {
        float* op = out + ((size_t)(b * CO_ + oc0 + oi) * H_ + h) * W_;
        float4 v0, v1;
        v0.x = (&acc[0].x)[oi]; v0.y = (&acc[1].x)[oi];
        v0.z = (&acc[2].x)[oi]; v0.w = (&acc[3].x)[oi];
        v1.x = (&acc[4].x)[oi]; v1.y = (&acc[5].x)[oi];
        v1.z = (&acc[6].x)[oi]; v1.w = (&acc[7].x)[oi];
        *(float4*)(op + gpa) = v0;
        *(float4*)(op + gpb) = v1;
    }
}

extern "C" void kernel_launch(void* const* d_in, const int* in_sizes, int n_in,
                              void* d_out, int out_size, void* d_ws, size_t ws_size,
                              hipStream_t stream) {
    const float* x  = (const float*)d_in[0];
    const float* wp = (const float*)d_in[1];
    const float* bp = (const float*)d_in[2];
    const float* wd = (const float*)d_in[3];
    float* out = (float*)d_out;
    float* ws  = (float*)d_ws;

    float* xt  = ws + XT_OFF;
    float* off = ws + OFF_OFF;
    float* wt  = ws + WT_OFF;
    float* wpt = ws + WPT_OFF;

    transpose_x_k<<<B_ * H_ * (W_ / 64), 256, 0, stream>>>(x, xt);
    transpose_w_k<<<(K_ * C_ * CO_ + 255) / 256, 256, 0, stream>>>(wd, wp, wt, wpt);
    offset_conv_k<<<B_ * H_ * 2, 256, 0, stream>>>(x, wpt, bp, off);
    deform_gemm_k<<<B_ * H_, 256, 0, stream>>>(xt, off, wt, out);
}

// Round 4
// 214.233 us; speedup vs baseline: 1.6616x; 1.1845x over previous
//
#include <hip/hip_runtime.h>

// DCNv1 on MI355X. fp32 throughout (no fp32 MFMA on CDNA4 -> VALU GEMM).
// Shapes fixed: B=4, C=64, H=W=128, Cout=64, K=3x3, stride=1, pad=1.

constexpr int B_  = 4;
constexpr int C_  = 64;
constexpr int H_  = 128;
constexpr int W_  = 128;
constexpr int CO_ = 64;
constexpr int K_  = 9;     // 3x3
constexpr int HW_ = H_ * W_;

// ---------------- workspace layout (floats) ----------------
constexpr size_t XT_OFF  = 0;                                   // NHWC x [B][H][W][C]
constexpr size_t OFF_OFF = XT_OFF + (size_t)B_ * HW_ * C_;      // offsets [B][H][W][18]
constexpr size_t WT_OFF  = OFF_OFF + (size_t)B_ * HW_ * 18;     // w_d^T [k][c][oc]
constexpr size_t WPT_OFF = WT_OFF + (size_t)K_ * C_ * CO_;      // w_p^T [c][t][j]

// ---------------- K0a: x NCHW -> NHWC ----------------
__global__ __launch_bounds__(256) void transpose_x_k(const float* __restrict__ x,
                                                     float* __restrict__ xt) {
    __shared__ float tile[64][65];
    int bid = blockIdx.x;           // B*H*(W/64) = 1024
    int wt  = bid & 1;
    int h   = (bid >> 1) & 127;
    int b   = bid >> 8;
    int w0  = wt * 64;
    int tid = threadIdx.x;

    int lw = tid & 63;
    int c0 = tid >> 6;
#pragma unroll
    for (int i = 0; i < 16; ++i) {
        int c = c0 * 16 + i;
        tile[c][lw] = x[((b * C_ + c) * H_ + h) * W_ + w0 + lw];
    }
    __syncthreads();
    int lc = tid & 63;
    int wp = tid >> 6;
#pragma unroll
    for (int i = 0; i < 16; ++i) {
        int w = wp * 16 + i;
        xt[((size_t)(b * H_ + h) * W_ + w0 + w) * C_ + lc] = tile[lc][w];
    }
}

// ---------------- K0b: weight transposes (tiny) ----------------
__global__ void transpose_w_k(const float* __restrict__ wd, const float* __restrict__ wp,
                              float* __restrict__ wt, float* __restrict__ wpt) {
    int i = blockIdx.x * 256 + threadIdx.x;
    if (i < K_ * C_ * CO_) {                 // wt[k][c][oc] = wd[oc][c][k]
        int k  = i / (C_ * CO_);
        int r  = i % (C_ * CO_);
        int c  = r / CO_;
        int oc = r % CO_;
        wt[i] = wd[(oc * C_ + c) * K_ + k];
    }
    if (i < C_ * K_ * 18) {                  // wpt[c][t][j] = wp[j][c][ky][kx]
        int j = i % 18;
        int t = (i / 18) % K_;
        int c = i / (18 * K_);
        wpt[i] = wp[((j * C_ + c) * 3 + t / 3) * 3 + (t % 3)];
    }
}

// ---------------- K1: offset conv v3 ----------------
// Block: 64 pixels x 4 c-quarters = 256 threads. Grid = B*H*2 = 1024.
// KEY FIX: readfirstlane makes the c-quarter provably wave-uniform, so
// weight rows go through the s_load (scalar) path instead of per-lane
// broadcast global_load_dword (v2's hidden ~2600 VMEM ops/thread).
__global__ __launch_bounds__(256) void offset_conv_k(const float* __restrict__ x,
                                                     const float* __restrict__ wpt,
                                                     const float* __restrict__ bp,
                                                     float* __restrict__ off) {
    __shared__ float red[4][64][19];
    int tid = threadIdx.x;
    int pix = tid & 63;
    int cqu = __builtin_amdgcn_readfirstlane(tid >> 6);  // wave-uniform 0..3
    int bid = blockIdx.x;
    int w0  = (bid & 1) * 64;
    int h   = (bid >> 1) & 127;
    int b   = bid >> 8;
    int wo  = w0 + pix;

    float acc[18];
#pragma unroll
    for (int j = 0; j < 18; ++j) acc[j] = 0.f;

    int c0 = cqu * 16;
    for (int ci = 0; ci < 16; ++ci) {
        int c = c0 + ci;
        const float* xb = x + (size_t)(b * C_ + c) * HW_;   // SGPR base
        const float* wr = wpt + (c * 9) * 18;               // SGPR base -> s_load
#pragma unroll
        for (int t = 0; t < 9; ++t) {
            int y  = h + t / 3 - 1;
            int xw = wo + (t % 3) - 1;
            float xv = (y >= 0 && y < H_ && xw >= 0 && xw < W_) ? xb[y * W_ + xw] : 0.f;
            const float* wrow = wr + t * 18;
#pragma unroll
            for (int j = 0; j < 18; ++j) acc[j] = fmaf(xv, wrow[j], acc[j]);
        }
    }
#pragma unroll
    for (int j = 0; j < 18; ++j) red[cqu][pix][j] = acc[j];
    __syncthreads();

    size_t base = ((size_t)(b * H_ + h) * W_ + w0) * 18;
#pragma unroll
    for (int it = 0; it < 5; ++it) {
        int idx = it * 256 + tid;
        if (idx < 64 * 18) {
            int p = idx / 18, j = idx % 18;
            float s = red[0][p][j] + red[1][p][j] + red[2][p][j] + red[3][p][j] + bp[j];
            off[base + idx] = s;
        }
    }
}

// ---------------- K2: deformable sampling + GEMM v4 ----------------
// Block: 64 pixels x 64 oc, 256 threads, thread tile 4pix x 4oc.
// 32KB LDS -> up to 5 blocks/CU; grid = 1024 -> ~4 resident blocks/CU for
// cross-block staging/GEMM overlap. XCD slab swizzle retained.
__global__ __launch_bounds__(256) void deform_gemm_k(const float* __restrict__ xt,
                                                     const float* __restrict__ off,
                                                     const float* __restrict__ wt,
                                                     float* __restrict__ out) {
    __shared__ float s_samp[64][64];   // [c][pix] 16KB
    __shared__ float s_w[64][64];      // [c][oc]  16KB

    int tid = threadIdx.x;
    // XCD-aware mapping: xcd = bid&7 owns a contiguous 64-row slab of one image.
    int bid = blockIdx.x;              // 0..1023
    int xcd = bid & 7;
    int idx = bid >> 3;                // 0..127
    int b   = xcd >> 1;
    int h   = ((xcd & 1) << 6) | (idx >> 1);
    int w0  = (idx & 1) * 64;

    // staging roles: pix = lane, c-quarter = wave (naturally uniform)
    int spix = tid & 63;
    int scg  = tid >> 6;               // 16 channels each
    // GEMM roles: 4 pixels x 4 oc per thread
    int gp  = (tid & 15) * 4;
    int oc0 = (tid >> 4) * 4;

    float4 acc[4];                     // acc[pi] = 4 oc values for pixel gp+pi
#pragma unroll
    for (int i = 0; i < 4; ++i) acc[i] = make_float4(0.f, 0.f, 0.f, 0.f);

    size_t obase = ((size_t)(b * H_ + h) * W_ + w0 + spix) * 18;
    const float* xb = xt + (size_t)b * HW_ * C_;

    for (int k = 0; k < 9; ++k) {
        // ---- stage w tile: 4096 floats coalesced ----
        const float4* wsrc = (const float4*)(wt + k * 4096);
        float4* wdst = (float4*)&s_w[0][0];
#pragma unroll
        for (int i = 0; i < 4; ++i) wdst[i * 256 + tid] = wsrc[i * 256 + tid];

        // ---- stage samp tile (bilinear, 16 channels per thread) ----
        {
            float2 o2 = *(const float2*)(off + obase + 2 * k);
            float py = o2.x + (float)(h - 1 + k / 3);
            float px = o2.y + (float)(w0 + spix - 1 + (k % 3));
            float fy = floorf(py), fx = floorf(px);
            float wy = py - fy, wx = px - fx;
            int y0 = (int)fy, x0 = (int)fx;
            int y1 = y0 + 1,  x1 = x0 + 1;
            float w00 = (1.f - wy) * (1.f - wx);
            float w01 = (1.f - wy) * wx;
            float w10 = wy * (1.f - wx);
            float w11 = wy * wx;
            bool vy0 = (y0 >= 0) & (y0 < H_), vy1 = (y1 >= 0) & (y1 < H_);
            bool vx0 = (x0 >= 0) & (x0 < W_), vx1 = (x1 >= 0) & (x1 < W_);
            w00 *= (float)(vy0 & vx0);
            w01 *= (float)(vy0 & vx1);
            w10 *= (float)(vy1 & vx0);
            w11 *= (float)(vy1 & vx1);
            int cy0 = min(max(y0, 0), H_ - 1), cy1 = min(max(y1, 0), H_ - 1);
            int cx0 = min(max(x0, 0), W_ - 1), cx1 = min(max(x1, 0), W_ - 1);
            int c0 = scg * 16;
            const float4* p00 = (const float4*)(xb + ((size_t)cy0 * W_ + cx0) * C_ + c0);
            const float4* p01 = (const float4*)(xb + ((size_t)cy0 * W_ + cx1) * C_ + c0);
            const float4* p10 = (const float4*)(xb + ((size_t)cy1 * W_ + cx0) * C_ + c0);
            const float4* p11 = (const float4*)(xb + ((size_t)cy1 * W_ + cx1) * C_ + c0);
#pragma unroll
            for (int i = 0; i < 4; ++i) {
                float4 a = p00[i], bq = p01[i], cq = p10[i], dq = p11[i];
                int c = c0 + i * 4;
                s_samp[c + 0][spix] = w00 * a.x + w01 * bq.x + w10 * cq.x + w11 * dq.x;
                s_samp[c + 1][spix] = w00 * a.y + w01 * bq.y + w10 * cq.y + w11 * dq.y;
                s_samp[c + 2][spix] = w00 * a.z + w01 * bq.z + w10 * cq.z + w11 * dq.z;
                s_samp[c + 3][spix] = w00 * a.w + w01 * bq.w + w10 * cq.w + w11 * dq.w;
            }
        }
        __syncthreads();

        // ---- GEMM: acc[pi] += s_w[c][oc0..3] * s_samp[c][gp+pi] ----
        // b128 reads: 16 distinct addrs x 16B stride (+broadcast) -> conflict-free
#pragma unroll 4
        for (int c = 0; c < 64; ++c) {
            float4 wv = *(const float4*)&s_w[c][oc0];
            float4 sa = *(const float4*)&s_samp[c][gp];
            acc[0].x = fmaf(wv.x, sa.x, acc[0].x);
            acc[0].y = fmaf(wv.y, sa.x, acc[0].y);
            acc[0].z = fmaf(wv.z, sa.x, acc[0].z);
            acc[0].w = fmaf(wv.w, sa.x, acc[0].w);
            acc[1].x = fmaf(wv.x, sa.y, acc[1].x);
            acc[1].y = fmaf(wv.y, sa.y, acc[1].y);
            acc[1].z = fmaf(wv.z, sa.y, acc[1].z);
            acc[1].w = fmaf(wv.w, sa.y, acc[1].w);
            acc[2].x = fmaf(wv.x, sa.z, acc[2].x);
            acc[2].y = fmaf(wv.y, sa.z, acc[2].y);
            acc[2].z = fmaf(wv.z, sa.z, acc[2].z);
            acc[2].w = fmaf(wv.w, sa.z, acc[2].w);
            acc[3].x = fmaf(wv.x, sa.w, acc[3].x);
            acc[3].y = fmaf(wv.y, sa.w, acc[3].y);
            acc[3].z = fmaf(wv.z, sa.w, acc[3].z);
            acc[3].w = fmaf(wv.w, sa.w, acc[3].w);
        }
        __syncthreads();
    }

    // ---- epilogue: NCHW output, one float4 store per oc ----
#pragma unroll
    for (int oi = 0; oi < 4; ++oi) {
        float4 v;
        v.x = (&acc[0].x)[oi];
        v.y = (&acc[1].x)[oi];
        v.z = (&acc[2].x)[oi];
        v.w = (&acc[3].x)[oi];
        *(float4*)&out[((size_t)(b * CO_ + oc0 + oi) * H_ + h) * W_ + w0 + gp] = v;
    }
}

extern "C" void kernel_launch(void* const* d_in, const int* in_sizes, int n_in,
                              void* d_out, int out_size, void* d_ws, size_t ws_size,
                              hipStream_t stream) {
    const float* x  = (const float*)d_in[0];
    const float* wp = (const float*)d_in[1];
    const float* bp = (const float*)d_in[2];
    const float* wd = (const float*)d_in[3];
    float* out = (float*)d_out;
    float* ws  = (float*)d_ws;

    float* xt  = ws + XT_OFF;
    float* off = ws + OFF_OFF;
    float* wt  = ws + WT_OFF;
    float* wpt = ws + WPT_OFF;

    transpose_x_k<<<B_ * H_ * (W_ / 64), 256, 0, stream>>>(x, xt);
    transpose_w_k<<<(K_ * C_ * CO_ + 255) / 256, 256, 0, stream>>>(wd, wp, wt, wpt);
    offset_conv_k<<<B_ * H_ * 2, 256, 0, stream>>>(x, wpt, bp, off);
    deform_gemm_k<<<B_ * HW_ / 64, 256, 0, stream>>>(xt, off, wt, out);
}

// Round 5
// 200.448 us; speedup vs baseline: 1.7759x; 1.0688x over previous
//
#include <hip/hip_runtime.h>

// DCNv1 on MI355X. Deform-GEMM via bf16x3 MFMA (hi/lo split, 3 passes -> ~fp32
// precision). Shapes fixed: B=4, C=64, H=W=128, Cout=64, K=3x3, stride=1, pad=1.

constexpr int B_  = 4;
constexpr int C_  = 64;
constexpr int H_  = 128;
constexpr int W_  = 128;
constexpr int CO_ = 64;
constexpr int K_  = 9;
constexpr int HW_ = H_ * W_;

typedef short bf16x8 __attribute__((ext_vector_type(8)));
typedef float f32x4  __attribute__((ext_vector_type(4)));

// ---------------- workspace layout (float units) ----------------
constexpr size_t XT_OFF   = 0;                                    // NHWC x f32
constexpr size_t OFF_OFF  = XT_OFF + (size_t)B_ * HW_ * C_;       // offsets f32
constexpr size_t WPT2_OFF = OFF_OFF + (size_t)B_ * HW_ * 18;      // w_p^T [c][t][20] f32
constexpr size_t WDH_OFF  = WPT2_OFF + (size_t)C_ * K_ * 20;      // w_d hi bf16 [k][oc][c]
constexpr size_t WDL_OFF  = WDH_OFF + (size_t)K_ * CO_ * C_ / 2;  // w_d lo bf16

__device__ inline short f2bf(float x) {                 // RTN f32->bf16
    unsigned u = __float_as_uint(x);
    return (short)((u + 0x7FFF + ((u >> 16) & 1)) >> 16);
}
__device__ inline float bf2f(short s) {
    return __uint_as_float(((unsigned)(unsigned short)s) << 16);
}

// ---------------- K0a: x NCHW -> NHWC ----------------
__global__ __launch_bounds__(256) void transpose_x_k(const float* __restrict__ x,
                                                     float* __restrict__ xt) {
    __shared__ float tile[64][65];
    int bid = blockIdx.x;           // 1024
    int wt  = bid & 1;
    int h   = (bid >> 1) & 127;
    int b   = bid >> 8;
    int w0  = wt * 64;
    int tid = threadIdx.x;
    int lw = tid & 63, c0 = tid >> 6;
#pragma unroll
    for (int i = 0; i < 16; ++i) {
        int c = c0 * 16 + i;
        tile[c][lw] = x[((b * C_ + c) * H_ + h) * W_ + w0 + lw];
    }
    __syncthreads();
    int lc = tid & 63, wp = tid >> 6;
#pragma unroll
    for (int i = 0; i < 16; ++i) {
        int w = wp * 16 + i;
        xt[((size_t)(b * H_ + h) * W_ + w0 + w) * C_ + lc] = tile[lc][w];
    }
}

// ---------------- K0b: weight prep ----------------
// wdh/wdl[k][oc][c] = bf16 hi/lo split of wd[oc][c][k]; wpt2[c][t][20] padded.
__global__ void transpose_w_k(const float* __restrict__ wd, const float* __restrict__ wp,
                              short* __restrict__ wdh, short* __restrict__ wdl,
                              float* __restrict__ wpt2) {
    int i = blockIdx.x * 256 + threadIdx.x;
    if (i < K_ * CO_ * C_) {               // 36864
        int k  = i / (CO_ * C_);
        int r  = i % (CO_ * C_);
        int oc = r >> 6;
        int c  = r & 63;
        float v = wd[(oc * C_ + c) * K_ + k];
        short h = f2bf(v);
        wdh[i] = h;
        wdl[i] = f2bf(v - bf2f(h));
    }
    if (i < C_ * K_ * 20) {                // 11520
        int j = i % 20;
        int t = (i / 20) % K_;
        int c = i / (20 * K_);
        wpt2[i] = (j < 18) ? wp[((j * C_ + c) * 3 + t / 3) * 3 + (t % 3)] : 0.f;
    }
}

// ---------------- K1: offset conv v4 (pixel-pair tiling) ----------------
// Block: 128 pix (row) as 64 pairs x 4 c-quarters = 256 thr. Grid = B*H = 512.
// 2 pixels per thread -> each scalar weight load feeds 2 FMAs; waves/CU halved.
__global__ __launch_bounds__(256) void offset_conv_k(const float* __restrict__ x,
                                                     const float* __restrict__ wpt2,
                                                     const float* __restrict__ bp,
                                                     float* __restrict__ off) {
    __shared__ float red[4][128][19];
    int tid = threadIdx.x;
    int pp  = tid & 63;
    int cg  = __builtin_amdgcn_readfirstlane(tid >> 6);  // wave-uniform 0..3
    int h   = blockIdx.x & 127;
    int b   = blockIdx.x >> 7;

    float acc0[18], acc1[18];
#pragma unroll
    for (int j = 0; j < 18; ++j) { acc0[j] = 0.f; acc1[j] = 0.f; }

    int c0 = cg * 16;
    for (int ci = 0; ci < 16; ++ci) {
        int c = c0 + ci;
        const float* xb = x + (size_t)(b * C_ + c) * HW_;   // SGPR base
        const float* wr = wpt2 + c * 180;                    // SGPR base -> s_load
#pragma unroll
        for (int t = 0; t < 9; ++t) {
            int y   = h + t / 3 - 1;
            int xw0 = pp + (t % 3) - 1;
            int xw1 = xw0 + 64;
            bool yv = (y >= 0) & (y < H_);
            float xv0 = (yv && xw0 >= 0) ? xb[y * W_ + xw0] : 0.f;            // xw0<127 always
            float xv1 = (yv && xw1 < W_) ? xb[y * W_ + xw1] : 0.f;            // xw1>=0 always
            const float* wrow = wr + t * 20;
#pragma unroll
            for (int j = 0; j < 18; ++j) {
                float wj = wrow[j];
                acc0[j] = fmaf(xv0, wj, acc0[j]);
                acc1[j] = fmaf(xv1, wj, acc1[j]);
            }
        }
    }
#pragma unroll
    for (int j = 0; j < 18; ++j) {
        red[cg][pp][j]      = acc0[j];
        red[cg][pp + 64][j] = acc1[j];
    }
    __syncthreads();

    size_t base = ((size_t)(b * H_ + h) * W_) * 18;
#pragma unroll
    for (int it = 0; it < 9; ++it) {
        int idx = it * 256 + tid;           // 0..2303 = 128pix*18j
        int p = idx / 18, j = idx % 18;
        float s = red[0][p][j] + red[1][p][j] + red[2][p][j] + red[3][p][j] + bp[j];
        off[base + idx] = s;
    }
}

// ---------------- K2: deform sampling + bf16x3 MFMA GEMM ----------------
// Block: 128 pix (one row) x 64 oc, 256 thr = 4 waves. Wave w -> oc tile
// [16w,16w+16); 8 pixel N-tiles. Per tap: stage samples (bilinear f32 ->
// bf16 hi/lo, [pix][c] row-major, XOR-swizzled) + weights ([oc][c]), then
// 2 K-steps x 8 N-tiles x 3 mfma passes. D layout: col=lane&15 (pix),
// row=(lane>>4)*4+reg (oc). A/B frags: lane&15 = own row, k=(lane>>4)*8+j.
__global__ __launch_bounds__(256) void deform_gemm_k(const float* __restrict__ xt,
                                                     const float* __restrict__ off,
                                                     const short* __restrict__ wdh,
                                                     const short* __restrict__ wdl,
                                                     float* __restrict__ out) {
    __shared__ __align__(16) short s_sh[128 * 64];   // samples hi [pix][c] 16KB
    __shared__ __align__(16) short s_sl[128 * 64];   // samples lo       16KB
    __shared__ __align__(16) short s_wh[64 * 64];    // weights hi [oc][c] 8KB
    __shared__ __align__(16) short s_wl[64 * 64];    // weights lo        8KB

    int tid = threadIdx.x;
    int bid = blockIdx.x;              // 512
    int xcd = bid & 7;                 // XCD slab swizzle (L2 locality)
    int idx = bid >> 3;                // 0..63
    int b   = xcd >> 1;
    int h   = ((xcd & 1) << 6) | idx;

    // staging roles
    int pix   = tid & 127;
    int chalf = tid >> 7;              // 32 channels each
    // GEMM roles
    int lane = tid & 63;
    int wv   = tid >> 6;               // wave -> oc tile
    int l4   = lane & 15;
    int lq   = lane >> 4;
    int ocA  = wv * 16 + l4;           // A-operand row this lane loads

    f32x4 acc[8];
#pragma unroll
    for (int i = 0; i < 8; ++i) acc[i] = (f32x4){0.f, 0.f, 0.f, 0.f};

    size_t obase = ((size_t)(b * H_ + h) * W_ + pix) * 18;
    const float* xb = xt + (size_t)b * HW_ * C_;

    for (int k = 0; k < 9; ++k) {
        // ---- stage weight tap: 4096 bf16 per array, swizzled ----
#pragma unroll
        for (int i = 0; i < 2; ++i) {
            int e    = (i * 256 + tid) * 8;          // element index (8 shorts)
            int row  = e >> 6;
            int colb = (e & 63) * 2;
            int db   = (row * 128 + colb) ^ ((row & 7) << 4);
            *(bf16x8*)((char*)s_wh + db) = *(const bf16x8*)(wdh + k * 4096 + e);
            *(bf16x8*)((char*)s_wl + db) = *(const bf16x8*)(wdl + k * 4096 + e);
        }
        // ---- stage samples: bilinear 32 c per thread, split hi/lo ----
        {
            float2 o2 = *(const float2*)(off + obase + 2 * k);
            float py = o2.x + (float)(h - 1 + k / 3);
            float px = o2.y + (float)(pix - 1 + (k % 3));
            float fy = floorf(py), fx = floorf(px);
            float wy = py - fy, wx = px - fx;
            int y0 = (int)fy, x0 = (int)fx;
            int y1 = y0 + 1,  x1 = x0 + 1;
            float w00 = (1.f - wy) * (1.f - wx);
            float w01 = (1.f - wy) * wx;
            float w10 = wy * (1.f - wx);
            float w11 = wy * wx;
            bool vy0 = (y0 >= 0) & (y0 < H_), vy1 = (y1 >= 0) & (y1 < H_);
            bool vx0 = (x0 >= 0) & (x0 < W_), vx1 = (x1 >= 0) & (x1 < W_);
            w00 *= (float)(vy0 & vx0);
            w01 *= (float)(vy0 & vx1);
            w10 *= (float)(vy1 & vx0);
            w11 *= (float)(vy1 & vx1);
            int cy0 = min(max(y0, 0), H_ - 1), cy1 = min(max(y1, 0), H_ - 1);
            int cx0 = min(max(x0, 0), W_ - 1), cx1 = min(max(x1, 0), W_ - 1);
            int c0 = chalf * 32;
            const float4* p00 = (const float4*)(xb + ((size_t)cy0 * W_ + cx0) * C_ + c0);
            const float4* p01 = (const float4*)(xb + ((size_t)cy0 * W_ + cx1) * C_ + c0);
            const float4* p10 = (const float4*)(xb + ((size_t)cy1 * W_ + cx0) * C_ + c0);
            const float4* p11 = (const float4*)(xb + ((size_t)cy1 * W_ + cx1) * C_ + c0);
            float sv[32];
#pragma unroll
            for (int i = 0; i < 8; ++i) {
                float4 a = p00[i], bq = p01[i], cq = p10[i], dq = p11[i];
                sv[i * 4 + 0] = w00 * a.x + w01 * bq.x + w10 * cq.x + w11 * dq.x;
                sv[i * 4 + 1] = w00 * a.y + w01 * bq.y + w10 * cq.y + w11 * dq.y;
                sv[i * 4 + 2] = w00 * a.z + w01 * bq.z + w10 * cq.z + w11 * dq.z;
                sv[i * 4 + 3] = w00 * a.w + w01 * bq.w + w10 * cq.w + w11 * dq.w;
            }
#pragma unroll
            for (int i = 0; i < 4; ++i) {
                bf16x8 hv, lv;
#pragma unroll
                for (int j = 0; j < 8; ++j) {
                    float s = sv[i * 8 + j];
                    short hs = f2bf(s);
                    hv[j] = hs;
                    lv[j] = f2bf(s - bf2f(hs));
                }
                int db = (pix * 128 + c0 * 2 + i * 16) ^ ((pix & 7) << 4);
                *(bf16x8*)((char*)s_sh + db) = hv;
                *(bf16x8*)((char*)s_sl + db) = lv;
            }
        }
        __syncthreads();

        // ---- GEMM: 2 K-steps x 8 N-tiles x 3 passes ----
#pragma unroll
        for (int ks = 0; ks < 2; ++ks) {
            int ab = (ocA * 128 + ks * 64 + lq * 16) ^ ((ocA & 7) << 4);
            bf16x8 ah = *(const bf16x8*)((char*)s_wh + ab);
            bf16x8 al = *(const bf16x8*)((char*)s_wl + ab);
#pragma unroll
            for (int nt = 0; nt < 8; ++nt) {
                int prow = nt * 16 + l4;
                int bb = (prow * 128 + ks * 64 + lq * 16) ^ ((prow & 7) << 4);
                bf16x8 bh = *(const bf16x8*)((char*)s_sh + bb);
                bf16x8 bl = *(const bf16x8*)((char*)s_sl + bb);
                acc[nt] = __builtin_amdgcn_mfma_f32_16x16x32_bf16(ah, bh, acc[nt], 0, 0, 0);
                acc[nt] = __builtin_amdgcn_mfma_f32_16x16x32_bf16(ah, bl, acc[nt], 0, 0, 0);
                acc[nt] = __builtin_amdgcn_mfma_f32_16x16x32_bf16(al, bh, acc[nt], 0, 0, 0);
            }
        }
        __syncthreads();
    }

    // ---- epilogue: D col=lane&15 -> pix, row=(lane>>4)*4+r -> oc ----
    int oc0 = wv * 16 + lq * 4;
#pragma unroll
    for (int nt = 0; nt < 8; ++nt) {
#pragma unroll
        for (int r = 0; r < 4; ++r) {
            out[((size_t)(b * CO_ + oc0 + r) * H_ + h) * W_ + nt * 16 + l4] = acc[nt][r];
        }
    }
}

extern "C" void kernel_launch(void* const* d_in, const int* in_sizes, int n_in,
                              void* d_out, int out_size, void* d_ws, size_t ws_size,
                              hipStream_t stream) {
    const float* x  = (const float*)d_in[0];
    const float* wp = (const float*)d_in[1];
    const float* bp = (const float*)d_in[2];
    const float* wd = (const float*)d_in[3];
    float* out = (float*)d_out;
    float* ws  = (float*)d_ws;

    float* xt   = ws + XT_OFF;
    float* off  = ws + OFF_OFF;
    float* wpt2 = ws + WPT2_OFF;
    short* wdh  = (short*)(ws + WDH_OFF);
    short* wdl  = (short*)(ws + WDL_OFF);

    transpose_x_k<<<B_ * H_ * (W_ / 64), 256, 0, stream>>>(x, xt);
    transpose_w_k<<<(K_ * CO_ * C_ + 255) / 256, 256, 0, stream>>>(wd, wp, wdh, wdl, wpt2);
    offset_conv_k<<<B_ * H_, 256, 0, stream>>>(x, wpt2, bp, off);
    deform_gemm_k<<<B_ * H_, 256, 0, stream>>>(xt, off, wdh, wdl, out);
}